// Round 3
// baseline (243.343 us; speedup 1.0000x reference)
//
#include <hip/hip_runtime.h>
#include <stdint.h>

#define N_NODES 4096
#define F_DIM   256
#define BATCH   8

typedef __attribute__((ext_vector_type(8))) __bf16 bf16x8;
typedef __attribute__((ext_vector_type(4))) float  f32x4;
typedef __attribute__((ext_vector_type(8))) unsigned short u16x8;

typedef const __attribute__((address_space(1))) void* gas1_t;
typedef __attribute__((address_space(3))) void*       las3_t;

__device__ __forceinline__ void stage16(const void* g, void* l) {
  __builtin_amdgcn_global_load_lds((gas1_t)g, (las3_t)l, 16, 0, 0);
}

__device__ __forceinline__ unsigned short f2bf(float f) {
  union { float f; uint32_t u; } v; v.f = f;
  uint32_t u = v.u;
  return (unsigned short)((u + 0x7FFFu + ((u >> 16) & 1u)) >> 16); // RTNE
}
__device__ __forceinline__ float bf2f(unsigned short u) {
  union { uint32_t u; float f; } v; v.u = ((uint32_t)u) << 16;
  return v.f;
}
__device__ __forceinline__ float dinv_of(float d) {
  return d > 0.f ? 1.0f / sqrtf(d) : 0.f;
}

// ---------------- k_pre: fused H/W bf16 casts + symmetrize+degree ----------------
// Transposed-Sb phase now reads row-contiguous from a post-relu transposed copy
// (Tt reused) instead of 8-way-bank-conflicted column reads of T1.
__global__ __launch_bounds__(256) void k_pre(const float* __restrict__ A,
                                             unsigned short* __restrict__ Sb,
                                             float* __restrict__ D,
                                             const float4* __restrict__ H4,
                                             ushort4* __restrict__ Hb4,
                                             const float* __restrict__ W,
                                             unsigned short* __restrict__ Wt) {
  int t = threadIdx.x;
  int bid = blockIdx.y * 64 + blockIdx.x;
  {
    int i = bid * 512 + t;
    float4 v = H4[i];
    ushort4 o; o.x = f2bf(v.x); o.y = f2bf(v.y); o.z = f2bf(v.z); o.w = f2bf(v.w);
    Hb4[i] = o;
    i += 256;
    v = H4[i];
    o.x = f2bf(v.x); o.y = f2bf(v.y); o.z = f2bf(v.z); o.w = f2bf(v.w);
    Hb4[i] = o;
  }
  if (bid < 256) Wt[t * 256 + bid] = f2bf(W[bid * 256 + t]);

  int bi = blockIdx.y, bj = blockIdx.x;
  if (bj < bi) return;

  __shared__ __align__(16) float T1[64][68];  // A(bi,bj) tile, then v (row-major)
  __shared__ float Tt[64][67];                // A(bj,bi)^T, then v^T
  __shared__ float Pr4[64][4];
  __shared__ float Pc[4][64];
  int i0 = bi * 64, j0 = bj * 64;

#pragma unroll
  for (int it = 0; it < 4; ++it) {
    int idx = it * 256 + t;
    int r = idx >> 4, c4 = (idx & 15) * 4;
    float4 v1 = *(const float4*)(A + (size_t)(i0 + r) * N_NODES + j0 + c4);
    *(float4*)&T1[r][c4] = v1;
    float4 v2 = *(const float4*)(A + (size_t)(j0 + r) * N_NODES + i0 + c4);
    Tt[c4 + 0][r] = v2.x; Tt[c4 + 1][r] = v2.y; Tt[c4 + 2][r] = v2.z; Tt[c4 + 3][r] = v2.w;
  }
  __syncthreads();

  // compute (reads only): thread owns row r, cols {cb..cb+7} u {cb+32..cb+39}
  int r = t >> 2, cb = (t & 3) * 8;
  float vv[16];
  float rowpart = 0.f;
#pragma unroll
  for (int g = 0; g < 2; ++g) {
    int c0 = cb + g * 32;
#pragma unroll
    for (int i = 0; i < 8; ++i) {
      float v = 0.5f * (T1[r][c0 + i] + Tt[r][c0 + i]);
      v = v > 0.f ? v : 0.f;
      vv[g * 8 + i] = v;
      rowpart += v;
    }
  }
  __syncthreads();  // all reads of raw T1/Tt done before overwrite

  // write phase: Sb rows, T1 = v (for colsum), Tt = v^T (for transposed output)
#pragma unroll
  for (int g = 0; g < 2; ++g) {
    int c0 = cb + g * 32;
    u16x8 u;
#pragma unroll
    for (int i = 0; i < 8; ++i) u[i] = f2bf(vv[g * 8 + i]);
    *(u16x8*)&Sb[(size_t)(i0 + r) * N_NODES + j0 + c0] = u;
    *(float4*)&T1[r][c0]     = make_float4(vv[g*8+0], vv[g*8+1], vv[g*8+2], vv[g*8+3]);
    *(float4*)&T1[r][c0 + 4] = make_float4(vv[g*8+4], vv[g*8+5], vv[g*8+6], vv[g*8+7]);
#pragma unroll
    for (int i = 0; i < 8; ++i) Tt[c0 + i][r] = vv[g * 8 + i];
  }
  Pr4[r][t & 3] = rowpart;
  __syncthreads();

  {
    int c = t & 63, seg = t >> 6;
    float s = 0.f;
#pragma unroll
    for (int i = 0; i < 16; ++i) s += T1[seg * 16 + i][c];
    Pc[seg][c] = s;
  }
  __syncthreads();

  if (t < 64) {
    atomicAdd(&D[i0 + t], Pr4[t][0] + Pr4[t][1] + Pr4[t][2] + Pr4[t][3]);
  } else if (t < 128 && bi != bj) {
    int c = t - 64;
    atomicAdd(&D[j0 + c], Pc[0][c] + Pc[1][c] + Pc[2][c] + Pc[3][c]);
  }

  if (bi != bj) {
    // transposed Sb write: row-contiguous reads from Tt (conflict-light)
#pragma unroll
    for (int it = 0; it < 2; ++it) {
      int u = it * 256 + t;
      int co = u >> 3, rc = (u & 7) * 8;
      u16x8 o;
#pragma unroll
      for (int i = 0; i < 8; ++i) o[i] = f2bf(Tt[co][rc + i]);
      *(u16x8*)&Sb[(size_t)(j0 + co) * N_NODES + i0 + rc] = o;
    }
  }
}

// ---------------- GEMM1: single-shot K=256; writes HWb + fragment-major Gt2 ----
// Gt2 layout: B-fragment (rbg = row/16, kt = k/64, ks = (k/32)&1) is 1 KB
// contiguous; lane slot l holds row rbg*16+(l&15), k-bytes (ks*32+(l>>4)*8)*2.
// So gemm2 loads a fragment with one coalesced dwordx4 at base + lane*16.
__global__ __launch_bounds__(512) void k_gemm1(const unsigned short* __restrict__ Hb,
                                               const unsigned short* __restrict__ Wt,
                                               const float* __restrict__ D,
                                               unsigned short* __restrict__ HWb,
                                               unsigned short* __restrict__ Gt2) {
  __shared__ __align__(16) unsigned short L[65536];  // As | Ws, 128 KB
  int t = threadIdx.x;
  int lane = t & 63, r16 = lane & 15, q = lane >> 4;
  int wave = t >> 6;
  int wm = wave >> 2, wn = wave & 3;
  int nh = blockIdx.x;
  int m0 = blockIdx.y * 128;
  int n0 = nh * 128;

#pragma unroll
  for (int i = 0; i < 8; ++i) {
    int s = i * 512 + t;
    int row = s >> 5, cl = s & 31;
    int cs = cl ^ (row & 7);
    uint32_t dst = (uint32_t)(i * 512 + (t & ~63)) * 16;
    stage16(Hb + (size_t)(m0 + row) * 256 + cs * 8, (char*)L + dst);
    stage16(Wt + (size_t)(n0 + row) * 256 + cs * 8, (char*)L + 65536 + dst);
  }
  __syncthreads();

  f32x4 acc[4][2];
#pragma unroll
  for (int i = 0; i < 4; ++i)
#pragma unroll
    for (int j = 0; j < 2; ++j) acc[i][j] = f32x4{0.f, 0.f, 0.f, 0.f};

#pragma unroll
  for (int ks = 0; ks < 8; ++ks) {
    bf16x8 a[4], b[2];
#pragma unroll
    for (int mi = 0; mi < 4; ++mi) {
      int ra = wm * 64 + mi * 16 + r16;
      a[mi] = *(const bf16x8*)((const char*)L + ra * 512 + (((ks * 4 + q) ^ (ra & 7)) << 4));
    }
#pragma unroll
    for (int ni = 0; ni < 2; ++ni) {
      int rb = wn * 32 + ni * 16 + r16;
      b[ni] = *(const bf16x8*)((const char*)L + 65536 + rb * 512 + (((ks * 4 + q) ^ (rb & 7)) << 4));
    }
#pragma unroll
    for (int mi = 0; mi < 4; ++mi)
#pragma unroll
      for (int ni = 0; ni < 2; ++ni)
        acc[mi][ni] = __builtin_amdgcn_mfma_f32_16x16x32_bf16(a[mi], b[ni], acc[mi][ni], 0, 0, 0);
  }
  __syncthreads();

  unsigned short (*T)[136] = (unsigned short (*)[136])L;
#pragma unroll
  for (int mi = 0; mi < 4; ++mi) {
    int rowl = wm * 64 + mi * 16 + q * 4;
#pragma unroll
    for (int ni = 0; ni < 2; ++ni) {
      int coll = wn * 32 + ni * 16 + r16;
#pragma unroll
      for (int rr = 0; rr < 4; ++rr) {
        unsigned short h = f2bf(acc[mi][ni][rr]);
        HWb[(size_t)(m0 + rowl + rr) * F_DIM + (n0 + coll)] = h;
        T[coll][rowl + rr] = h;
      }
    }
  }
  __syncthreads();

  int b = m0 >> 12, nb = m0 & 4095;
#pragma unroll
  for (int i = 0; i < 4; ++i) {
    int u = i * 512 + t;
    int co = u >> 4, cs = (u & 15) * 8;
    u16x8 v = *(const u16x8*)&T[co][cs];
    float4 d0 = *(const float4*)&D[nb + cs];
    float4 d1 = *(const float4*)&D[nb + cs + 4];
    u16x8 w;
    w[0] = f2bf(bf2f(v[0]) * dinv_of(d0.x));
    w[1] = f2bf(bf2f(v[1]) * dinv_of(d0.y));
    w[2] = f2bf(bf2f(v[2]) * dinv_of(d0.z));
    w[3] = f2bf(bf2f(v[3]) * dinv_of(d0.w));
    w[4] = f2bf(bf2f(v[4]) * dinv_of(d1.x));
    w[5] = f2bf(bf2f(v[5]) * dinv_of(d1.y));
    w[6] = f2bf(bf2f(v[6]) * dinv_of(d1.z));
    w[7] = f2bf(bf2f(v[7]) * dinv_of(d1.w));
    // fragment-major Gt2 address
    int r_g = b * 256 + n0 + co;          // global B-row (0..2047)
    int k   = nb + cs;                    // 8-aligned k
    int rbg = r_g >> 4, rl = r_g & 15;
    int ktv = k >> 6, ksv = (k >> 5) & 1, qv = (k >> 3) & 3;
    size_t addr = ((((size_t)rbg * 64 + ktv) * 2 + ksv) * 64 + (qv * 16 + rl)) * 16;
    *(u16x8*)((char*)Gt2 + addr) = w;
  }
}

// ---------------- GEMM2: A via LDS (3-buf counted-vmcnt), B via registers ------
// Tile 256x128, 8 waves 4Mx2N, wave tile 64x64. LDS = 3 x 32 KB (A only).
// B-frags loaded coalesced from fragment-major Gt2, prefetched 1 tile ahead
// into ping-pong register sets (static indexing via named arrays, rule #20).
__global__ __launch_bounds__(512, 2) void k_gemm2(const unsigned short* __restrict__ Sb,
                                                  const unsigned short* __restrict__ Gt2,
                                                  const unsigned short* __restrict__ HWb,
                                                  const float* __restrict__ D,
                                                  float* __restrict__ Out) {
  __shared__ __align__(16) unsigned short LDS[3 * 16384];  // 96 KB
  int t = threadIdx.x;
  int lane = t & 63, r16 = lane & 15, q = lane >> 4;
  int wave = t >> 6;
  int wm = wave >> 1, wn = wave & 1;

  // XCD patch swizzle: 256 blocks; per-XCD 4mt x 8nt patch for L2 locality
  int bid = blockIdx.x;
  int xcd = bid & 7, j = bid >> 3;
  int mt = (xcd >> 1) * 4 + (j & 3);
  int nt = (xcd & 1) * 8 + (j >> 2);
  int m0 = mt * 256, n0 = nt * 128;

  // A staging: 4 global_load_lds per thread per tile; pre-swizzled source
  const char* aSrc[4];
  uint32_t aDst[4];
#pragma unroll
  for (int i = 0; i < 4; ++i) {
    int slot = i * 512 + t;
    int row = slot >> 3;
    int c = (slot & 7) ^ (row & 7);
    aSrc[i] = (const char*)Sb + (size_t)(m0 + row) * 8192 + c * 16;
    aDst[i] = (uint32_t)(i * 512 + (t & ~63)) * 16;
  }

  // A ds_read offsets (swizzle-matched)
  int aoff[4][2];
#pragma unroll
  for (int mi = 0; mi < 4; ++mi) {
    int ra = wm * 64 + mi * 16 + r16;
#pragma unroll
    for (int ks = 0; ks < 2; ++ks)
      aoff[mi][ks] = ra * 128 + (((ks * 4 + q) ^ (ra & 7)) << 4);
  }

  // B fragment base pointers: frag (rbg, kt, ks) at ((rbg*64+kt)*2+ks)*1024
  const char* bbase[4];
#pragma unroll
  for (int ni = 0; ni < 4; ++ni) {
    int rbg = nt * 8 + wn * 4 + ni;
    bbase[ni] = (const char*)Gt2 + (size_t)rbg * 131072 + lane * 16;
  }

  f32x4 acc[4][4];
#pragma unroll
  for (int i = 0; i < 4; ++i)
#pragma unroll
    for (int jj = 0; jj < 4; ++jj) acc[i][jj] = f32x4{0.f, 0.f, 0.f, 0.f};

  bf16x8 B0[4][2], B1[4][2];

  auto stage_tile = [&](int kt2, uint32_t bufByte) {
    size_t kb = (size_t)kt2 * 128;
#pragma unroll
    for (int i = 0; i < 4; ++i)
      stage16(aSrc[i] + kb, (char*)LDS + bufByte + aDst[i]);
  };

  // body: mode 2 = loadB(kt+1)+stage(kt+2)+vmcnt(12)+bar
  //       mode 1 = loadB(kt+1)+vmcnt(8)+bar ; mode 0 = final, no sync
  auto body = [&](int kt, uint32_t cur, bf16x8 (&Bu)[4][2], bf16x8 (&Bl)[4][2], int mode) {
    bf16x8 aR[4][2];
#pragma unroll
    for (int mi = 0; mi < 4; ++mi)
#pragma unroll
      for (int ks = 0; ks < 2; ++ks)
        aR[mi][ks] = *(const bf16x8*)((const char*)LDS + cur + aoff[mi][ks]);
    if (mode != 0) {
      size_t ko = (size_t)(kt + 1) * 2048;
#pragma unroll
      for (int ni = 0; ni < 4; ++ni)
#pragma unroll
        for (int ks = 0; ks < 2; ++ks)
          Bl[ni][ks] = *(const bf16x8*)(bbase[ni] + ko + ks * 1024);
    }
    if (mode == 2) {
      uint32_t stg = cur + 65536;
      if (stg >= 98304) stg -= 98304;
      stage_tile(kt + 2, stg);
    }
    __builtin_amdgcn_s_setprio(1);
#pragma unroll
    for (int ks = 0; ks < 2; ++ks)
#pragma unroll
      for (int mi = 0; mi < 4; ++mi)
#pragma unroll
        for (int ni = 0; ni < 4; ++ni)
          acc[mi][ni] = __builtin_amdgcn_mfma_f32_16x16x32_bf16(aR[mi][ks], Bu[ni][ks], acc[mi][ni], 0, 0, 0);
    __builtin_amdgcn_s_setprio(0);
    if (mode == 2) {
      asm volatile("s_waitcnt vmcnt(12)" ::: "memory");  // drain A(kt+1) staging
      __builtin_amdgcn_s_barrier();
      __builtin_amdgcn_sched_barrier(0);
    } else if (mode == 1) {
      asm volatile("s_waitcnt vmcnt(8)" ::: "memory");   // drain A(kt+1)
      __builtin_amdgcn_s_barrier();
      __builtin_amdgcn_sched_barrier(0);
    }
  };

  // prologue: B(0) -> B0; stage A(0)->buf0, A(1)->buf1; drain B(0)+A(0)
#pragma unroll
  for (int ni = 0; ni < 4; ++ni)
#pragma unroll
    for (int ks = 0; ks < 2; ++ks)
      B0[ni][ks] = *(const bf16x8*)(bbase[ni] + ks * 1024);
  stage_tile(0, 0);
  stage_tile(1, 32768);
  asm volatile("s_waitcnt vmcnt(4)" ::: "memory");
  __builtin_amdgcn_s_barrier();
  __builtin_amdgcn_sched_barrier(0);

  uint32_t cur = 0;
#pragma unroll 1
  for (int kt = 0; kt < 62; kt += 2) {
    body(kt, cur, B0, B1, 2);
    cur += 32768; if (cur == 98304) cur = 0;
    body(kt + 1, cur, B1, B0, 2);
    cur += 32768; if (cur == 98304) cur = 0;
  }
  body(62, cur, B0, B1, 1);
  cur += 32768; if (cur == 98304) cur = 0;
  body(63, cur, B1, B0, 0);

  // epilogue: Out = relu(HW - dinv(D[row]) * acc)
  int bq = n0 >> 8;
#pragma unroll
  for (int mi = 0; mi < 4; ++mi) {
    int row = m0 + wm * 64 + mi * 16 + q * 4;
    float di[4];
#pragma unroll
    for (int rr = 0; rr < 4; ++rr) di[rr] = dinv_of(D[row + rr]);
#pragma unroll
    for (int ni = 0; ni < 4; ++ni) {
      int col = n0 + wn * 64 + ni * 16 + r16;
      int o = col & 255;
#pragma unroll
      for (int rr = 0; rr < 4; ++rr) {
        size_t oi = ((size_t)bq * N_NODES + (row + rr)) * F_DIM + o;
        float u = bf2f(HWb[oi]) - di[rr] * acc[mi][ni][rr];
        Out[oi] = u > 0.f ? u : 0.f;
      }
    }
  }
}

extern "C" void kernel_launch(void* const* d_in, const int* in_sizes, int n_in,
                              void* d_out, int out_size, void* d_ws, size_t ws_size,
                              hipStream_t stream) {
  (void)in_sizes; (void)n_in; (void)out_size; (void)ws_size;
  const float* H = (const float*)d_in[0];
  const float* W = (const float*)d_in[1];
  const float* A = (const float*)d_in[2];
  float* out = (float*)d_out;

  char* ws = (char*)d_ws;
  size_t off = 0;
  auto alloc = [&](size_t bytes) {
    char* p = ws + off;
    off += (bytes + 255) & ~(size_t)255;
    return p;
  };
  float*          Dd   = (float*)alloc((size_t)N_NODES * 4);
  unsigned short* Sb   = (unsigned short*)alloc((size_t)N_NODES * N_NODES * 2);        // 32 MB
  unsigned short* HWb  = (unsigned short*)alloc((size_t)BATCH * N_NODES * F_DIM * 2);  // 16 MB
  unsigned short* Gt2  = (unsigned short*)alloc((size_t)BATCH * F_DIM * N_NODES * 2);  // 16 MB
  unsigned short* Wt   = (unsigned short*)alloc((size_t)F_DIM * F_DIM * 2);
  unsigned short* Hb   = (unsigned short*)alloc((size_t)BATCH * N_NODES * F_DIM * 2);  // 16 MB

  hipMemsetAsync(Dd, 0, N_NODES * 4, stream);
  k_pre<<<dim3(64, 64), 256, 0, stream>>>(A, Sb, Dd, (const float4*)H, (ushort4*)Hb, W, Wt);
  k_gemm1<<<dim3(2, 256), 512, 0, stream>>>(Hb, Wt, Dd, HWb, Gt2);
  k_gemm2<<<dim3(256), 512, 0, stream>>>(Sb, Gt2, HWb, Dd, out);
}

// Round 4
// 232.822 us; speedup vs baseline: 1.0452x; 1.0452x over previous
//
#include <hip/hip_runtime.h>
#include <stdint.h>

#define N_NODES 4096
#define F_DIM   256
#define BATCH   8

typedef __attribute__((ext_vector_type(8))) __bf16 bf16x8;
typedef __attribute__((ext_vector_type(4))) float  f32x4;
typedef __attribute__((ext_vector_type(8))) unsigned short u16x8;

typedef const __attribute__((address_space(1))) void* gas1_t;
typedef __attribute__((address_space(3))) void*       las3_t;

__device__ __forceinline__ void stage16(const void* g, void* l) {
  __builtin_amdgcn_global_load_lds((gas1_t)g, (las3_t)l, 16, 0, 0);
}

__device__ __forceinline__ unsigned short f2bf(float f) {
  union { float f; uint32_t u; } v; v.f = f;
  uint32_t u = v.u;
  return (unsigned short)((u + 0x7FFFu + ((u >> 16) & 1u)) >> 16); // RTNE
}
__device__ __forceinline__ float bf2f(unsigned short u) {
  union { uint32_t u; float f; } v; v.u = ((uint32_t)u) << 16;
  return v.f;
}
__device__ __forceinline__ float dinv_of(float d) {
  return d > 0.f ? 1.0f / sqrtf(d) : 0.f;
}

// ---------------- k_pre: fused H/W bf16 casts + symmetrize+degree ----------------
__global__ __launch_bounds__(256) void k_pre(const float* __restrict__ A,
                                             unsigned short* __restrict__ Sb,
                                             float* __restrict__ D,
                                             const float4* __restrict__ H4,
                                             ushort4* __restrict__ Hb4,
                                             const float* __restrict__ W,
                                             unsigned short* __restrict__ Wt) {
  int t = threadIdx.x;
  int bid = blockIdx.y * 64 + blockIdx.x;
  {
    int i = bid * 512 + t;
    float4 v = H4[i];
    ushort4 o; o.x = f2bf(v.x); o.y = f2bf(v.y); o.z = f2bf(v.z); o.w = f2bf(v.w);
    Hb4[i] = o;
    i += 256;
    v = H4[i];
    o.x = f2bf(v.x); o.y = f2bf(v.y); o.z = f2bf(v.z); o.w = f2bf(v.w);
    Hb4[i] = o;
  }
  if (bid < 256) Wt[t * 256 + bid] = f2bf(W[bid * 256 + t]);

  int bi = blockIdx.y, bj = blockIdx.x;
  if (bj < bi) return;

  __shared__ __align__(16) float T1[64][68];
  __shared__ float Tt[64][67];
  __shared__ float Pr4[64][4];
  __shared__ float Pc[4][64];
  int i0 = bi * 64, j0 = bj * 64;

#pragma unroll
  for (int it = 0; it < 4; ++it) {
    int idx = it * 256 + t;
    int r = idx >> 4, c4 = (idx & 15) * 4;
    float4 v1 = *(const float4*)(A + (size_t)(i0 + r) * N_NODES + j0 + c4);
    *(float4*)&T1[r][c4] = v1;
    float4 v2 = *(const float4*)(A + (size_t)(j0 + r) * N_NODES + i0 + c4);
    Tt[c4 + 0][r] = v2.x; Tt[c4 + 1][r] = v2.y; Tt[c4 + 2][r] = v2.z; Tt[c4 + 3][r] = v2.w;
  }
  __syncthreads();

  int r = t >> 2, cb = (t & 3) * 8;
  float vv[16];
  float rowpart = 0.f;
#pragma unroll
  for (int g = 0; g < 2; ++g) {
    int c0 = cb + g * 32;
#pragma unroll
    for (int i = 0; i < 8; ++i) {
      float v = 0.5f * (T1[r][c0 + i] + Tt[r][c0 + i]);
      v = v > 0.f ? v : 0.f;
      vv[g * 8 + i] = v;
      rowpart += v;
    }
  }
  __syncthreads();

#pragma unroll
  for (int g = 0; g < 2; ++g) {
    int c0 = cb + g * 32;
    u16x8 u;
#pragma unroll
    for (int i = 0; i < 8; ++i) u[i] = f2bf(vv[g * 8 + i]);
    *(u16x8*)&Sb[(size_t)(i0 + r) * N_NODES + j0 + c0] = u;
    *(float4*)&T1[r][c0]     = make_float4(vv[g*8+0], vv[g*8+1], vv[g*8+2], vv[g*8+3]);
    *(float4*)&T1[r][c0 + 4] = make_float4(vv[g*8+4], vv[g*8+5], vv[g*8+6], vv[g*8+7]);
#pragma unroll
    for (int i = 0; i < 8; ++i) Tt[c0 + i][r] = vv[g * 8 + i];
  }
  Pr4[r][t & 3] = rowpart;
  __syncthreads();

  {
    int c = t & 63, seg = t >> 6;
    float s = 0.f;
#pragma unroll
    for (int i = 0; i < 16; ++i) s += T1[seg * 16 + i][c];
    Pc[seg][c] = s;
  }
  __syncthreads();

  if (t < 64) {
    atomicAdd(&D[i0 + t], Pr4[t][0] + Pr4[t][1] + Pr4[t][2] + Pr4[t][3]);
  } else if (t < 128 && bi != bj) {
    int c = t - 64;
    atomicAdd(&D[j0 + c], Pc[0][c] + Pc[1][c] + Pc[2][c] + Pc[3][c]);
  }

  if (bi != bj) {
#pragma unroll
    for (int it = 0; it < 2; ++it) {
      int u = it * 256 + t;
      int co = u >> 3, rc = (u & 7) * 8;
      u16x8 o;
#pragma unroll
      for (int i = 0; i < 8; ++i) o[i] = f2bf(Tt[co][rc + i]);
      *(u16x8*)&Sb[(size_t)(j0 + co) * N_NODES + i0 + rc] = o;
    }
  }
}

// ---------------- GEMM1: single-shot K=256; writes HWb + fragment-major Gt2 ----
__global__ __launch_bounds__(512) void k_gemm1(const unsigned short* __restrict__ Hb,
                                               const unsigned short* __restrict__ Wt,
                                               const float* __restrict__ D,
                                               unsigned short* __restrict__ HWb,
                                               unsigned short* __restrict__ Gt2) {
  __shared__ __align__(16) unsigned short L[65536];
  int t = threadIdx.x;
  int lane = t & 63, r16 = lane & 15, q = lane >> 4;
  int wave = t >> 6;
  int wm = wave >> 2, wn = wave & 3;
  int nh = blockIdx.x;
  int m0 = blockIdx.y * 128;
  int n0 = nh * 128;

#pragma unroll
  for (int i = 0; i < 8; ++i) {
    int s = i * 512 + t;
    int row = s >> 5, cl = s & 31;
    int cs = cl ^ (row & 7);
    uint32_t dst = (uint32_t)(i * 512 + (t & ~63)) * 16;
    stage16(Hb + (size_t)(m0 + row) * 256 + cs * 8, (char*)L + dst);
    stage16(Wt + (size_t)(n0 + row) * 256 + cs * 8, (char*)L + 65536 + dst);
  }
  __syncthreads();

  f32x4 acc[4][2];
#pragma unroll
  for (int i = 0; i < 4; ++i)
#pragma unroll
    for (int j = 0; j < 2; ++j) acc[i][j] = f32x4{0.f, 0.f, 0.f, 0.f};

#pragma unroll
  for (int ks = 0; ks < 8; ++ks) {
    bf16x8 a[4], b[2];
#pragma unroll
    for (int mi = 0; mi < 4; ++mi) {
      int ra = wm * 64 + mi * 16 + r16;
      a[mi] = *(const bf16x8*)((const char*)L + ra * 512 + (((ks * 4 + q) ^ (ra & 7)) << 4));
    }
#pragma unroll
    for (int ni = 0; ni < 2; ++ni) {
      int rb = wn * 32 + ni * 16 + r16;
      b[ni] = *(const bf16x8*)((const char*)L + 65536 + rb * 512 + (((ks * 4 + q) ^ (rb & 7)) << 4));
    }
#pragma unroll
    for (int mi = 0; mi < 4; ++mi)
#pragma unroll
      for (int ni = 0; ni < 2; ++ni)
        acc[mi][ni] = __builtin_amdgcn_mfma_f32_16x16x32_bf16(a[mi], b[ni], acc[mi][ni], 0, 0, 0);
  }
  __syncthreads();

  unsigned short (*T)[136] = (unsigned short (*)[136])L;
#pragma unroll
  for (int mi = 0; mi < 4; ++mi) {
    int rowl = wm * 64 + mi * 16 + q * 4;
#pragma unroll
    for (int ni = 0; ni < 2; ++ni) {
      int coll = wn * 32 + ni * 16 + r16;
#pragma unroll
      for (int rr = 0; rr < 4; ++rr) {
        unsigned short h = f2bf(acc[mi][ni][rr]);
        HWb[(size_t)(m0 + rowl + rr) * F_DIM + (n0 + coll)] = h;
        T[coll][rowl + rr] = h;
      }
    }
  }
  __syncthreads();

  int b = m0 >> 12, nb = m0 & 4095;
#pragma unroll
  for (int i = 0; i < 4; ++i) {
    int u = i * 512 + t;
    int co = u >> 4, cs = (u & 15) * 8;
    u16x8 v = *(const u16x8*)&T[co][cs];
    float4 d0 = *(const float4*)&D[nb + cs];
    float4 d1 = *(const float4*)&D[nb + cs + 4];
    u16x8 w;
    w[0] = f2bf(bf2f(v[0]) * dinv_of(d0.x));
    w[1] = f2bf(bf2f(v[1]) * dinv_of(d0.y));
    w[2] = f2bf(bf2f(v[2]) * dinv_of(d0.z));
    w[3] = f2bf(bf2f(v[3]) * dinv_of(d0.w));
    w[4] = f2bf(bf2f(v[4]) * dinv_of(d1.x));
    w[5] = f2bf(bf2f(v[5]) * dinv_of(d1.y));
    w[6] = f2bf(bf2f(v[6]) * dinv_of(d1.z));
    w[7] = f2bf(bf2f(v[7]) * dinv_of(d1.w));
    int r_g = b * 256 + n0 + co;
    int k   = nb + cs;
    int rbg = r_g >> 4, rl = r_g & 15;
    int ktv = k >> 6, ksv = (k >> 5) & 1, qv = (k >> 3) & 3;
    size_t addr = ((((size_t)rbg * 64 + ktv) * 2 + ksv) * 64 + (qv * 16 + rl)) * 16;
    *(u16x8*)((char*)Gt2 + addr) = w;
  }
}

// ---------------- GEMM2: A via LDS (3-buf), B via DEPTH-2 register prefetch ----
// Body(kt): [stage A(kt+2)] [ds_read A(kt)] [MFMA w/ B(kt)] [load B(kt+2) into
// the slot B(kt) just freed — WAR keeps issue order] [vmcnt(12): drains
// stage(kt+1)+B(kt+1), leaves stage(kt+2)+B(kt+2) in flight] [barrier].
// B loads have ~2 bodies (~2500 cy) of latency slack vs R3's ~300 cy.
__global__ __launch_bounds__(512, 2) void k_gemm2(const unsigned short* __restrict__ Sb,
                                                  const unsigned short* __restrict__ Gt2,
                                                  const unsigned short* __restrict__ HWb,
                                                  const float* __restrict__ D,
                                                  float* __restrict__ Out) {
  __shared__ __align__(16) unsigned short LDS[3 * 16384];  // 96 KB (A only)
  int t = threadIdx.x;
  int lane = t & 63, r16 = lane & 15, q = lane >> 4;
  int wave = t >> 6;
  int wm = wave >> 1, wn = wave & 1;

  int bid = blockIdx.x;
  int xcd = bid & 7, j = bid >> 3;
  int mt = (xcd >> 1) * 4 + (j & 3);
  int nt = (xcd & 1) * 8 + (j >> 2);
  int m0 = mt * 256, n0 = nt * 128;

  const char* aSrc[4];
  uint32_t aDst[4];
#pragma unroll
  for (int i = 0; i < 4; ++i) {
    int slot = i * 512 + t;
    int row = slot >> 3;
    int c = (slot & 7) ^ (row & 7);
    aSrc[i] = (const char*)Sb + (size_t)(m0 + row) * 8192 + c * 16;
    aDst[i] = (uint32_t)(i * 512 + (t & ~63)) * 16;
  }

  int aoff[4][2];
#pragma unroll
  for (int mi = 0; mi < 4; ++mi) {
    int ra = wm * 64 + mi * 16 + r16;
#pragma unroll
    for (int ks = 0; ks < 2; ++ks)
      aoff[mi][ks] = ra * 128 + (((ks * 4 + q) ^ (ra & 7)) << 4);
  }

  const char* bbase[4];
#pragma unroll
  for (int ni = 0; ni < 4; ++ni) {
    int rbg = nt * 8 + wn * 4 + ni;
    bbase[ni] = (const char*)Gt2 + (size_t)rbg * 131072 + lane * 16;
  }

  f32x4 acc[4][4];
#pragma unroll
  for (int i = 0; i < 4; ++i)
#pragma unroll
    for (int jj = 0; jj < 4; ++jj) acc[i][jj] = f32x4{0.f, 0.f, 0.f, 0.f};

  bf16x8 B0[4][2], B1[4][2];  // depth-2 ping-pong (static indexing, rule #20)

  auto stage_tile = [&](int kt2, uint32_t bufByte) {
    size_t kb = (size_t)kt2 * 128;
#pragma unroll
    for (int i = 0; i < 4; ++i)
      stage16(aSrc[i] + kb, (char*)LDS + bufByte + aDst[i]);
  };
  auto load_B = [&](int kt2, bf16x8 (&Bd)[4][2]) {
    size_t ko = (size_t)kt2 * 2048;
#pragma unroll
    for (int ni = 0; ni < 4; ++ni)
#pragma unroll
      for (int ks = 0; ks < 2; ++ks)
        Bd[ni][ks] = *(const bf16x8*)(bbase[ni] + ko + ks * 1024);
  };

  // body: mode 2 = stage(kt+2) + MFMA + loadB(kt+2) + vmcnt(12) + bar
  //       mode 1 = MFMA + vmcnt(0) + bar ; mode 0 = final MFMA only
  auto body = [&](int kt, uint32_t cur, bf16x8 (&B)[4][2], int mode) {
    if (mode == 2) {
      uint32_t stg = cur + 65536;
      if (stg >= 98304) stg -= 98304;
      stage_tile(kt + 2, stg);
    }
    bf16x8 aR[4][2];
#pragma unroll
    for (int mi = 0; mi < 4; ++mi)
#pragma unroll
      for (int ks = 0; ks < 2; ++ks)
        aR[mi][ks] = *(const bf16x8*)((const char*)LDS + cur + aoff[mi][ks]);
    __builtin_amdgcn_s_setprio(1);
#pragma unroll
    for (int ks = 0; ks < 2; ++ks)
#pragma unroll
      for (int mi = 0; mi < 4; ++mi)
#pragma unroll
        for (int ni = 0; ni < 4; ++ni)
          acc[mi][ni] = __builtin_amdgcn_mfma_f32_16x16x32_bf16(aR[mi][ks], B[ni][ks], acc[mi][ni], 0, 0, 0);
    __builtin_amdgcn_s_setprio(0);
    if (mode == 2) {
      load_B(kt + 2, B);  // WAR on B regs: issues after MFMA reads
      asm volatile("s_waitcnt vmcnt(12)" ::: "memory");
      __builtin_amdgcn_s_barrier();
      __builtin_amdgcn_sched_barrier(0);
    } else if (mode == 1) {
      asm volatile("s_waitcnt vmcnt(0)" ::: "memory");
      __builtin_amdgcn_s_barrier();
      __builtin_amdgcn_sched_barrier(0);
    }
  };

  // prologue: B(0)->B0, B(1)->B1, stage A(0)->buf0, A(1)->buf1; keep stage(1) in flight
  load_B(0, B0);
  load_B(1, B1);
  stage_tile(0, 0);
  stage_tile(1, 32768);
  asm volatile("s_waitcnt vmcnt(4)" ::: "memory");
  __builtin_amdgcn_s_barrier();
  __builtin_amdgcn_sched_barrier(0);

  uint32_t cur = 0;
#pragma unroll 1
  for (int kt = 0; kt < 62; kt += 2) {
    body(kt, cur, B0, 2);
    cur += 32768; if (cur == 98304) cur = 0;
    body(kt + 1, cur, B1, 2);
    cur += 32768; if (cur == 98304) cur = 0;
  }
  body(62, cur, B0, 1);
  cur += 32768; if (cur == 98304) cur = 0;
  body(63, cur, B1, 0);

  int bq = n0 >> 8;
#pragma unroll
  for (int mi = 0; mi < 4; ++mi) {
    int row = m0 + wm * 64 + mi * 16 + q * 4;
    float di[4];
#pragma unroll
    for (int rr = 0; rr < 4; ++rr) di[rr] = dinv_of(D[row + rr]);
#pragma unroll
    for (int ni = 0; ni < 4; ++ni) {
      int col = n0 + wn * 64 + ni * 16 + r16;
      int o = col & 255;
#pragma unroll
      for (int rr = 0; rr < 4; ++rr) {
        size_t oi = ((size_t)bq * N_NODES + (row + rr)) * F_DIM + o;
        float u = bf2f(HWb[oi]) - di[rr] * acc[mi][ni][rr];
        Out[oi] = u > 0.f ? u : 0.f;
      }
    }
  }
}

extern "C" void kernel_launch(void* const* d_in, const int* in_sizes, int n_in,
                              void* d_out, int out_size, void* d_ws, size_t ws_size,
                              hipStream_t stream) {
  (void)in_sizes; (void)n_in; (void)out_size; (void)ws_size;
  const float* H = (const float*)d_in[0];
  const float* W = (const float*)d_in[1];
  const float* A = (const float*)d_in[2];
  float* out = (float*)d_out;

  char* ws = (char*)d_ws;
  size_t off = 0;
  auto alloc = [&](size_t bytes) {
    char* p = ws + off;
    off += (bytes + 255) & ~(size_t)255;
    return p;
  };
  float*          Dd   = (float*)alloc((size_t)N_NODES * 4);
  unsigned short* Sb   = (unsigned short*)alloc((size_t)N_NODES * N_NODES * 2);        // 32 MB
  unsigned short* HWb  = (unsigned short*)alloc((size_t)BATCH * N_NODES * F_DIM * 2);  // 16 MB
  unsigned short* Gt2  = (unsigned short*)alloc((size_t)BATCH * F_DIM * N_NODES * 2);  // 16 MB
  unsigned short* Wt   = (unsigned short*)alloc((size_t)F_DIM * F_DIM * 2);
  unsigned short* Hb   = (unsigned short*)alloc((size_t)BATCH * N_NODES * F_DIM * 2);  // 16 MB

  hipMemsetAsync(Dd, 0, N_NODES * 4, stream);
  k_pre<<<dim3(64, 64), 256, 0, stream>>>(A, Sb, Dd, (const float4*)H, (ushort4*)Hb, W, Wt);
  k_gemm1<<<dim3(2, 256), 512, 0, stream>>>(Hb, Wt, Dd, HWb, Gt2);
  k_gemm2<<<dim3(256), 512, 0, stream>>>(Sb, Gt2, HWb, Dd, out);
}

// Round 5
// 224.158 us; speedup vs baseline: 1.0856x; 1.0386x over previous
//
#include <hip/hip_runtime.h>
#include <stdint.h>

#define N_NODES 4096
#define F_DIM   256
#define BATCH   8

typedef __attribute__((ext_vector_type(8))) __bf16 bf16x8;
typedef __attribute__((ext_vector_type(4))) float  f32x4;
typedef __attribute__((ext_vector_type(8))) unsigned short u16x8;

typedef const __attribute__((address_space(1))) void* gas1_t;
typedef __attribute__((address_space(3))) void*       las3_t;

__device__ __forceinline__ void stage16(const void* g, void* l) {
  __builtin_amdgcn_global_load_lds((gas1_t)g, (las3_t)l, 16, 0, 0);
}

__device__ __forceinline__ unsigned short f2bf(float f) {
  union { float f; uint32_t u; } v; v.f = f;
  uint32_t u = v.u;
  return (unsigned short)((u + 0x7FFFu + ((u >> 16) & 1u)) >> 16); // RTNE
}
__device__ __forceinline__ float bf2f(unsigned short u) {
  union { uint32_t u; float f; } v; v.u = ((uint32_t)u) << 16;
  return v.f;
}
__device__ __forceinline__ float dinv_of(float d) {
  return d > 0.f ? 1.0f / sqrtf(d) : 0.f;
}

// ---------------- k_pre: H/W bf16 casts + symmetrize (NO atomics, NO degree) ----
__global__ __launch_bounds__(256) void k_pre(const float* __restrict__ A,
                                             unsigned short* __restrict__ Sb,
                                             const float4* __restrict__ H4,
                                             ushort4* __restrict__ Hb4,
                                             const float* __restrict__ W,
                                             unsigned short* __restrict__ Wt) {
  int t = threadIdx.x;
  int bid = blockIdx.y * 64 + blockIdx.x;
  {
    int i = bid * 512 + t;
    float4 v = H4[i];
    ushort4 o; o.x = f2bf(v.x); o.y = f2bf(v.y); o.z = f2bf(v.z); o.w = f2bf(v.w);
    Hb4[i] = o;
    i += 256;
    v = H4[i];
    o.x = f2bf(v.x); o.y = f2bf(v.y); o.z = f2bf(v.z); o.w = f2bf(v.w);
    Hb4[i] = o;
  }
  if (bid < 256) Wt[t * 256 + bid] = f2bf(W[bid * 256 + t]);

  int bi = blockIdx.y, bj = blockIdx.x;
  if (bj < bi) return;

  __shared__ __align__(16) float T1[64][68];  // A(bi,bj), row-major
  __shared__ float Tt[64][67];                // A(bj,bi)^T, later v^T
  int i0 = bi * 64, j0 = bj * 64;

#pragma unroll
  for (int it = 0; it < 4; ++it) {
    int idx = it * 256 + t;
    int r = idx >> 4, c4 = (idx & 15) * 4;
    float4 v1 = *(const float4*)(A + (size_t)(i0 + r) * N_NODES + j0 + c4);
    *(float4*)&T1[r][c4] = v1;
    float4 v2 = *(const float4*)(A + (size_t)(j0 + r) * N_NODES + i0 + c4);
    Tt[c4 + 0][r] = v2.x; Tt[c4 + 1][r] = v2.y; Tt[c4 + 2][r] = v2.z; Tt[c4 + 3][r] = v2.w;
  }
  __syncthreads();

  // compute phase (reads only): thread owns row r, cols {cb..cb+7} u {cb+32..cb+39}
  int r = t >> 2, cb = (t & 3) * 8;
  float vv[16];
#pragma unroll
  for (int g = 0; g < 2; ++g) {
    int c0 = cb + g * 32;
#pragma unroll
    for (int i = 0; i < 8; ++i) {
      float v = 0.5f * (T1[r][c0 + i] + Tt[r][c0 + i]);
      vv[g * 8 + i] = v > 0.f ? v : 0.f;
    }
  }

  // upper-triangle store straight from registers
#pragma unroll
  for (int g = 0; g < 2; ++g) {
    int c0 = cb + g * 32;
    u16x8 u;
#pragma unroll
    for (int i = 0; i < 8; ++i) u[i] = f2bf(vv[g * 8 + i]);
    *(u16x8*)&Sb[(size_t)(i0 + r) * N_NODES + j0 + c0] = u;
  }

  if (bi != bj) {
    __syncthreads();  // all raw Tt reads done before overwrite
#pragma unroll
    for (int g = 0; g < 2; ++g) {
      int c0 = cb + g * 32;
#pragma unroll
      for (int i = 0; i < 8; ++i) Tt[c0 + i][r] = vv[g * 8 + i];  // v^T
    }
    __syncthreads();
    // transposed store: row-contiguous reads from Tt
#pragma unroll
    for (int it = 0; it < 2; ++it) {
      int u = it * 256 + t;
      int co = u >> 3, rc = (u & 7) * 8;
      u16x8 o;
#pragma unroll
      for (int i = 0; i < 8; ++i) o[i] = f2bf(Tt[co][rc + i]);
      *(u16x8*)&Sb[(size_t)(j0 + co) * N_NODES + i0 + rc] = o;
    }
  }
}

// ---------------- k_deg: D[i] = sum_j Sb[i][j] — coalesced, no atomics ----------
__global__ __launch_bounds__(256) void k_deg(const unsigned short* __restrict__ Sb,
                                             float* __restrict__ D) {
  int wave = threadIdx.x >> 6, lane = threadIdx.x & 63;
  int row = blockIdx.x * 4 + wave;
  const unsigned short* p = Sb + (size_t)row * N_NODES + lane * 8;
  float s = 0.f;
#pragma unroll
  for (int i = 0; i < 8; ++i) {
    u16x8 v = *(const u16x8*)(p + i * 512);
#pragma unroll
    for (int j = 0; j < 8; ++j) s += bf2f(v[j]);
  }
#pragma unroll
  for (int off = 32; off >= 1; off >>= 1) s += __shfl_xor(s, off);
  if (lane == 0) D[row] = s;
}

// ---------------- GEMM1: single-shot K=256; HWb + row-major Gt (dinv-scaled) ----
__global__ __launch_bounds__(512) void k_gemm1(const unsigned short* __restrict__ Hb,
                                               const unsigned short* __restrict__ Wt,
                                               const float* __restrict__ D,
                                               unsigned short* __restrict__ HWb,
                                               unsigned short* __restrict__ Gt) {
  __shared__ __align__(16) unsigned short L[65536];  // As | Ws, 128 KB
  int t = threadIdx.x;
  int lane = t & 63, r16 = lane & 15, q = lane >> 4;
  int wave = t >> 6;
  int wm = wave >> 2, wn = wave & 3;
  int nh = blockIdx.x;
  int m0 = blockIdx.y * 128;
  int n0 = nh * 128;

#pragma unroll
  for (int i = 0; i < 8; ++i) {
    int s = i * 512 + t;
    int row = s >> 5, cl = s & 31;
    int cs = cl ^ (row & 7);
    uint32_t dst = (uint32_t)(i * 512 + (t & ~63)) * 16;
    stage16(Hb + (size_t)(m0 + row) * 256 + cs * 8, (char*)L + dst);
    stage16(Wt + (size_t)(n0 + row) * 256 + cs * 8, (char*)L + 65536 + dst);
  }
  __syncthreads();

  f32x4 acc[4][2];
#pragma unroll
  for (int i = 0; i < 4; ++i)
#pragma unroll
    for (int j = 0; j < 2; ++j) acc[i][j] = f32x4{0.f, 0.f, 0.f, 0.f};

#pragma unroll
  for (int ks = 0; ks < 8; ++ks) {
    bf16x8 a[4], b[2];
#pragma unroll
    for (int mi = 0; mi < 4; ++mi) {
      int ra = wm * 64 + mi * 16 + r16;
      a[mi] = *(const bf16x8*)((const char*)L + ra * 512 + (((ks * 4 + q) ^ (ra & 7)) << 4));
    }
#pragma unroll
    for (int ni = 0; ni < 2; ++ni) {
      int rb = wn * 32 + ni * 16 + r16;
      b[ni] = *(const bf16x8*)((const char*)L + 65536 + rb * 512 + (((ks * 4 + q) ^ (rb & 7)) << 4));
    }
#pragma unroll
    for (int mi = 0; mi < 4; ++mi)
#pragma unroll
      for (int ni = 0; ni < 2; ++ni)
        acc[mi][ni] = __builtin_amdgcn_mfma_f32_16x16x32_bf16(a[mi], b[ni], acc[mi][ni], 0, 0, 0);
  }
  __syncthreads();

  unsigned short (*T)[136] = (unsigned short (*)[136])L;
#pragma unroll
  for (int mi = 0; mi < 4; ++mi) {
    int rowl = wm * 64 + mi * 16 + q * 4;
#pragma unroll
    for (int ni = 0; ni < 2; ++ni) {
      int coll = wn * 32 + ni * 16 + r16;
#pragma unroll
      for (int rr = 0; rr < 4; ++rr) {
        unsigned short h = f2bf(acc[mi][ni][rr]);
        HWb[(size_t)(m0 + rowl + rr) * F_DIM + (n0 + coll)] = h;
        T[coll][rowl + rr] = h;
      }
    }
  }
  __syncthreads();

  int b = m0 >> 12, nb = m0 & 4095;
#pragma unroll
  for (int i = 0; i < 4; ++i) {
    int u = i * 512 + t;
    int co = u >> 4, cs = (u & 15) * 8;
    u16x8 v = *(const u16x8*)&T[co][cs];
    float4 d0 = *(const float4*)&D[nb + cs];
    float4 d1 = *(const float4*)&D[nb + cs + 4];
    u16x8 w;
    w[0] = f2bf(bf2f(v[0]) * dinv_of(d0.x));
    w[1] = f2bf(bf2f(v[1]) * dinv_of(d0.y));
    w[2] = f2bf(bf2f(v[2]) * dinv_of(d0.z));
    w[3] = f2bf(bf2f(v[3]) * dinv_of(d0.w));
    w[4] = f2bf(bf2f(v[4]) * dinv_of(d1.x));
    w[5] = f2bf(bf2f(v[5]) * dinv_of(d1.y));
    w[6] = f2bf(bf2f(v[6]) * dinv_of(d1.z));
    w[7] = f2bf(bf2f(v[7]) * dinv_of(d1.w));
    *(u16x8*)&Gt[(size_t)(b * 256 + n0 + co) * N_NODES + nb + cs] = w;
  }
}

// ---------------- GEMM2: R1's triple-buffered counted-vmcnt pipeline (proven) ---
#define LDSB 49152  // bytes per buffer: A 32768 + B 16384

__global__ __launch_bounds__(512, 2) void k_gemm2(const unsigned short* __restrict__ Sb,
                                                  const unsigned short* __restrict__ Gt,
                                                  const unsigned short* __restrict__ HWb,
                                                  const float* __restrict__ D,
                                                  float* __restrict__ Out) {
  __shared__ __align__(16) unsigned short LDS[3 * 24576];  // 147456 B
  const int NT = N_NODES / 64;
  int t = threadIdx.x;
  int lane = t & 63, r16 = lane & 15, q = lane >> 4;
  int wave = t >> 6;
  int wm = wave >> 1, wn = wave & 1;

  int bid = blockIdx.x;
  int xcd = bid & 7, j = bid >> 3;
  int mt = (xcd >> 1) * 4 + (j & 3);
  int nt = (xcd & 1) * 8 + (j >> 2);
  int m0 = mt * 256, n0 = nt * 128;

  const char* aSrc[4]; const char* bSrc[2];
  uint32_t aDst[4], bDst[2];
#pragma unroll
  for (int i = 0; i < 4; ++i) {
    int slot = i * 512 + t;
    int row = slot >> 3;
    int c = (slot & 7) ^ (row & 7);
    aSrc[i] = (const char*)Sb + (size_t)(m0 + row) * 8192 + c * 16;
    aDst[i] = (uint32_t)(i * 512 + (t & ~63)) * 16;
  }
#pragma unroll
  for (int i = 0; i < 2; ++i) {
    int slot = i * 512 + t;
    int row = slot >> 3;
    int c = (slot & 7) ^ (row & 7);
    bSrc[i] = (const char*)Gt + (size_t)(n0 + row) * 8192 + c * 16;
    bDst[i] = 32768u + (uint32_t)(i * 512 + (t & ~63)) * 16;
  }

  int aoff[4][2], boff[4][2];
#pragma unroll
  for (int mi = 0; mi < 4; ++mi) {
    int ra = wm * 64 + mi * 16 + r16;
#pragma unroll
    for (int ks = 0; ks < 2; ++ks)
      aoff[mi][ks] = ra * 128 + (((ks * 4 + q) ^ (ra & 7)) << 4);
  }
#pragma unroll
  for (int ni = 0; ni < 4; ++ni) {
    int rb = wn * 64 + ni * 16 + r16;
#pragma unroll
    for (int ks = 0; ks < 2; ++ks)
      boff[ni][ks] = 32768 + rb * 128 + (((ks * 4 + q) ^ (rb & 7)) << 4);
  }

  f32x4 acc[4][4];
#pragma unroll
  for (int i = 0; i < 4; ++i)
#pragma unroll
    for (int jj = 0; jj < 4; ++jj) acc[i][jj] = f32x4{0.f, 0.f, 0.f, 0.f};

  auto stage_tile = [&](int kt2, uint32_t bufByte) {
    size_t kb = (size_t)kt2 * 128;
#pragma unroll
    for (int i = 0; i < 4; ++i)
      stage16(aSrc[i] + kb, (char*)LDS + bufByte + aDst[i]);
#pragma unroll
    for (int i = 0; i < 2; ++i)
      stage16(bSrc[i] + kb, (char*)LDS + bufByte + bDst[i]);
  };

  auto tile_body = [&](int kt, uint32_t cur, int mode) {
    bf16x8 aR[4][2], bR[4][2];
#pragma unroll
    for (int mi = 0; mi < 4; ++mi)
#pragma unroll
      for (int ks = 0; ks < 2; ++ks)
        aR[mi][ks] = *(const bf16x8*)((const char*)LDS + cur + aoff[mi][ks]);
#pragma unroll
    for (int ni = 0; ni < 4; ++ni)
#pragma unroll
      for (int ks = 0; ks < 2; ++ks)
        bR[ni][ks] = *(const bf16x8*)((const char*)LDS + cur + boff[ni][ks]);
    if (mode == 2) {
      uint32_t stg = cur + 2 * LDSB;
      if (stg >= 3 * LDSB) stg -= 3 * LDSB;
      stage_tile(kt + 2, stg);
    }
    __builtin_amdgcn_sched_barrier(0);
    __builtin_amdgcn_s_setprio(1);
#pragma unroll
    for (int ks = 0; ks < 2; ++ks)
#pragma unroll
      for (int mi = 0; mi < 4; ++mi)
#pragma unroll
        for (int ni = 0; ni < 4; ++ni)
          acc[mi][ni] = __builtin_amdgcn_mfma_f32_16x16x32_bf16(aR[mi][ks], bR[ni][ks], acc[mi][ni], 0, 0, 0);
    __builtin_amdgcn_s_setprio(0);
    if (mode == 2) {
      asm volatile("s_waitcnt vmcnt(6)" ::: "memory");
    } else if (mode == 1) {
      asm volatile("s_waitcnt vmcnt(0)" ::: "memory");
    }
    if (mode != 0) {
      __builtin_amdgcn_s_barrier();
      __builtin_amdgcn_sched_barrier(0);
    }
  };

  stage_tile(0, 0);
  stage_tile(1, LDSB);
  asm volatile("s_waitcnt vmcnt(6)" ::: "memory");
  __builtin_amdgcn_s_barrier();
  __builtin_amdgcn_sched_barrier(0);

  uint32_t cur = 0;
#pragma unroll 1
  for (int kt = 0; kt < NT - 2; ++kt) {
    tile_body(kt, cur, 2);
    cur += LDSB; if (cur == 3 * LDSB) cur = 0;
  }
  tile_body(NT - 2, cur, 1);
  cur += LDSB; if (cur == 3 * LDSB) cur = 0;
  tile_body(NT - 1, cur, 0);

  int bq = n0 >> 8;
#pragma unroll
  for (int mi = 0; mi < 4; ++mi) {
    int row = m0 + wm * 64 + mi * 16 + q * 4;
    float di[4];
#pragma unroll
    for (int rr = 0; rr < 4; ++rr) di[rr] = dinv_of(D[row + rr]);
#pragma unroll
    for (int ni = 0; ni < 4; ++ni) {
      int col = n0 + wn * 64 + ni * 16 + r16;
      int o = col & 255;
#pragma unroll
      for (int rr = 0; rr < 4; ++rr) {
        size_t oi = ((size_t)bq * N_NODES + (row + rr)) * F_DIM + o;
        float u = bf2f(HWb[oi]) - di[rr] * acc[mi][ni][rr];
        Out[oi] = u > 0.f ? u : 0.f;
      }
    }
  }
}

extern "C" void kernel_launch(void* const* d_in, const int* in_sizes, int n_in,
                              void* d_out, int out_size, void* d_ws, size_t ws_size,
                              hipStream_t stream) {
  (void)in_sizes; (void)n_in; (void)out_size; (void)ws_size;
  const float* H = (const float*)d_in[0];
  const float* W = (const float*)d_in[1];
  const float* A = (const float*)d_in[2];
  float* out = (float*)d_out;

  char* ws = (char*)d_ws;
  size_t off = 0;
  auto alloc = [&](size_t bytes) {
    char* p = ws + off;
    off += (bytes + 255) & ~(size_t)255;
    return p;
  };
  float*          Dd   = (float*)alloc((size_t)N_NODES * 4);
  unsigned short* Sb   = (unsigned short*)alloc((size_t)N_NODES * N_NODES * 2);        // 32 MB
  unsigned short* HWb  = (unsigned short*)alloc((size_t)BATCH * N_NODES * F_DIM * 2);  // 16 MB
  unsigned short* Gt   = (unsigned short*)alloc((size_t)BATCH * F_DIM * N_NODES * 2);  // 16 MB
  unsigned short* Wt   = (unsigned short*)alloc((size_t)F_DIM * F_DIM * 2);
  unsigned short* Hb   = (unsigned short*)alloc((size_t)BATCH * N_NODES * F_DIM * 2);  // 16 MB

  k_pre<<<dim3(64, 64), 256, 0, stream>>>(A, Sb, (const float4*)H, (ushort4*)Hb, W, Wt);
  k_deg<<<1024, 256, 0, stream>>>(Sb, Dd);
  k_gemm1<<<dim3(2, 256), 512, 0, stream>>>(Hb, Wt, Dd, HWb, Gt);
  k_gemm2<<<dim3(256), 512, 0, stream>>>(Sb, Gt, HWb, Dd, out);
}